// Round 1
// baseline (13149.213 us; speedup 1.0000x reference)
//
#include <hip/hip_runtime.h>
#include <math.h>

#define NN 20000
#define NE 320000
#define NG 16

__device__ __forceinline__ float silu_f(float x){ return x / (1.0f + __expf(-x)); }

// ---------------- geometry: bessel embedding + spherical harmonics ----------------
__global__ void k_geom(const float* __restrict__ dR,
                       float* __restrict__ remb, float* __restrict__ sh1){
  int e = blockIdx.x*256 + threadIdx.x;
  if (e >= NE) return;
  float x = dR[3*e+0], y = dR[3*e+1], z = dR[3*e+2];
  float r = sqrtf(x*x + y*y + z*z);
  float rs = fmaxf(r, 1e-6f);
  float inv = 1.0f / rs;
  const float SQ3 = 1.7320508075688772f;
  sh1[3*e+0] = SQ3 * x * inv;
  sh1[3*e+1] = SQ3 * y * inv;
  sh1[3*e+2] = SQ3 * z * inv;
  float env;
  if (r < 3.5f) env = 1.0f;
  else if (r > 4.0f) env = 0.0f;
  else {
    float t = (r - 3.5f) * 2.0f;
    env = 0.5f * (cosf(3.14159265358979323846f * t) + 1.0f);
  }
  float c = 0.7071067811865476f * inv * env;   // sqrt(2/RMAX) / r_safe * env
  #pragma unroll
  for (int k=0;k<8;k++){
    float arg = (float)(k+1) * 0.7853981633974483f * rs;  // n*pi*r/RMAX
    remb[8*e+k] = c * sinf(arg);
  }
}

// ---------------- node embedding: s = nodes @ W_embed / sqrt(NEL) ----------------
__global__ void k_embed(const float* __restrict__ nodes, const float* __restrict__ W,
                        float* __restrict__ s){
  int idx = blockIdx.x*256 + threadIdx.x;   // N*64 exact
  int n = idx>>6, o = idx&63;
  float a = nodes[n*4+0]*W[o] + nodes[n*4+1]*W[64+o]
          + nodes[n*4+2]*W[128+o] + nodes[n*4+3]*W[192+o];
  s[idx] = 0.5f*a;
}

// ---------------- per-layer node linears: s1, v1, sc_s, sc_v ----------------
__global__ void k_node(const float* __restrict__ s, const float* __restrict__ v,
                       const float* __restrict__ attrs,
                       const float* __restrict__ W1s, const float* __restrict__ W1v,
                       const float* __restrict__ Wscs, const float* __restrict__ Wscv,
                       float* __restrict__ s1, float* __restrict__ v1,
                       float* __restrict__ scs, float* __restrict__ scv){
  __shared__ float ls[4][64];
  __shared__ float lv[4][96];
  __shared__ float la[4][4];
  int tid = threadIdx.x;
  int nb = blockIdx.x*4;
  {
    int j = tid>>6, q = tid&63;
    ls[j][q] = s[(nb+j)*64+q];
  }
  for (int i=tid;i<384;i+=256){
    int j = i/96, q = i-96*j;
    lv[j][q] = v[(nb+j)*96+q];
  }
  if (tid<16) la[tid>>2][tid&3] = attrs[(nb+(tid>>2))*4 + (tid&3)];
  __syncthreads();
  int j = tid>>6, q = tid&63;
  int n = nb+j;
  // s1 = s @ W1s / 8   (one output per thread)
  {
    float acc=0.0f;
    #pragma unroll 8
    for (int i=0;i<64;i++) acc += ls[j][i]*W1s[i*64+q];
    s1[n*64+q] = acc*0.125f;
  }
  // sc_s[o] = sum_{i,e} s_i * attr_e * Wscs[i,e,o] / 16   (96 outputs)
  #pragma unroll 1
  for (int o=q;o<96;o+=64){
    float acc=0.0f;
    #pragma unroll 4
    for (int i=0;i<64;i++){
      float sv = ls[j][i];
      const float* wp = Wscs + (i*4)*96 + o;
      acc += sv*(la[j][0]*wp[0] + la[j][1]*wp[96] + la[j][2]*wp[192] + la[j][3]*wp[288]);
    }
    scs[n*96+o] = acc*0.0625f;
  }
  // v1[o,c] = sum_i v[i,c]*W1v[i,o] / sqrt(32)   (96 flat outputs)
  #pragma unroll 1
  for (int f=q;f<96;f+=64){
    int op=f/3, c=f-3*op;
    float acc=0.0f;
    #pragma unroll 8
    for (int i=0;i<32;i++) acc += lv[j][i*3+c]*W1v[i*32+op];
    v1[n*96+f] = acc*0.17677669529663687f;
  }
  // sc_v[o,c] = sum_{i,e} v[i,c]*attr_e*Wscv[i,e,o] / sqrt(128)
  #pragma unroll 1
  for (int f=q;f<96;f+=64){
    int op=f/3, c=f-3*op;
    float acc=0.0f;
    #pragma unroll 4
    for (int i=0;i<32;i++){
      float vv = lv[j][i*3+c];
      const float* wp = Wscv + (i*4)*32 + op;
      acc += vv*(la[j][0]*wp[0] + la[j][1]*wp[32] + la[j][2]*wp[64] + la[j][3]*wp[96]);
    }
    scv[n*96+f] = acc*0.08838834764831845f;
  }
}

// ---------------- per-layer edge kernel: radial MLP + message + atomic scatter ----------------
__launch_bounds__(256, 2)
__global__ void k_edge(const float* __restrict__ remb, const float* __restrict__ sh1,
                       const int* __restrict__ senders, const int* __restrict__ receivers,
                       const float* __restrict__ s1, const float* __restrict__ v1,
                       const float* __restrict__ R0, const float* __restrict__ R1,
                       const float* __restrict__ R2,
                       float* __restrict__ a_s, float* __restrict__ a_v){
  __shared__ __align__(16) float lR1[64*64];    // 16 KB
  __shared__ __align__(16) float lR2[64*192];   // 48 KB
  int tid = threadIdx.x;
  for (int i=tid;i<4096;i+=256)  lR1[i]=R1[i];
  for (int i=tid;i<12288;i+=256) lR2[i]=R2[i];
  __syncthreads();
  int e = blockIdx.x*256 + tid;   // exact: 1250*256 = 320000
  float rb[8];
  #pragma unroll
  for (int k=0;k<8;k++) rb[k]=remb[8*e+k];
  // h1 = silu(remb @ R0 / sqrt(8))
  float h1[64];
  #pragma unroll
  for (int j=0;j<64;j+=4){
    float a0=0,a1=0,a2=0,a3=0;
    #pragma unroll
    for (int k=0;k<8;k++){
      float r = rb[k];
      const float* wp = R0 + k*64 + j;   // uniform address -> scalar loads
      a0 = fmaf(r, wp[0], a0); a1 = fmaf(r, wp[1], a1);
      a2 = fmaf(r, wp[2], a2); a3 = fmaf(r, wp[3], a3);
    }
    h1[j+0]=silu_f(a0*0.3535533905932738f);
    h1[j+1]=silu_f(a1*0.3535533905932738f);
    h1[j+2]=silu_f(a2*0.3535533905932738f);
    h1[j+3]=silu_f(a3*0.3535533905932738f);
  }
  // h2 = silu(h1 @ R1 / 8)
  float h2[64];
  #pragma unroll
  for (int j=0;j<64;j+=4){
    float a0=0,a1=0,a2=0,a3=0;
    #pragma unroll
    for (int k=0;k<64;k++){
      float h = h1[k];
      float4 w4 = *(const float4*)(lR1 + k*64 + j);
      a0 = fmaf(h,w4.x,a0); a1 = fmaf(h,w4.y,a1);
      a2 = fmaf(h,w4.z,a2); a3 = fmaf(h,w4.w,a3);
    }
    h2[j+0]=silu_f(a0*0.125f);
    h2[j+1]=silu_f(a1*0.125f);
    h2[j+2]=silu_f(a2*0.125f);
    h2[j+3]=silu_f(a3*0.125f);
  }
  int src = senders[e], dst = receivers[e];
  float sx=sh1[3*e+0], sy=sh1[3*e+1], sz=sh1[3*e+2];
  const float* srow = s1 + (size_t)src*64;
  const float* vrow = v1 + (size_t)src*96;
  float* asr = a_s + (size_t)dst*96;
  float* avr = a_v + (size_t)dst*288;
  // channels 0..63: w1 (m_s) and w2 (m_v = w2*se*sh1)
  #pragma unroll 1
  for (int o=0;o<64;o+=4){
    float w10=0,w11=0,w12=0,w13=0, w20=0,w21=0,w22=0,w23=0;
    #pragma unroll
    for (int k=0;k<64;k++){
      float h = h2[k];
      float4 wa = *(const float4*)(lR2 + k*192 + o);
      float4 wb = *(const float4*)(lR2 + k*192 + 64 + o);
      w10=fmaf(h,wa.x,w10); w11=fmaf(h,wa.y,w11); w12=fmaf(h,wa.z,w12); w13=fmaf(h,wa.w,w13);
      w20=fmaf(h,wb.x,w20); w21=fmaf(h,wb.y,w21); w22=fmaf(h,wb.z,w22); w23=fmaf(h,wb.w,w23);
    }
    float4 se4 = *(const float4*)(srow + o);
    float sev[4] = {se4.x, se4.y, se4.z, se4.w};
    float w1a[4] = {w10,w11,w12,w13};
    float w2a[4] = {w20,w21,w22,w23};
    #pragma unroll
    for (int u=0;u<4;u++){
      // 0.03125 = (1/8 for R2-norm) * (1/4 for 1/sqrt(NNB))
      atomicAdd(asr+o+u, 0.03125f*w1a[u]*sev[u]);
      float m = 0.03125f*w2a[u]*sev[u];
      atomicAdd(avr+(o+u)*3+0, m*sx);
      atomicAdd(avr+(o+u)*3+1, m*sy);
      atomicAdd(avr+(o+u)*3+2, m*sz);
    }
  }
  // channels 64..95: w3 (m_v = w3*ve) and w4 (m_s = w4*dot(ve,sh1)/sqrt3)
  #pragma unroll 1
  for (int i0=0;i0<32;i0+=4){
    float w30=0,w31=0,w32=0,w33=0, w40=0,w41=0,w42=0,w43=0;
    #pragma unroll
    for (int k=0;k<64;k++){
      float h = h2[k];
      float4 wa = *(const float4*)(lR2 + k*192 + 128 + i0);
      float4 wb = *(const float4*)(lR2 + k*192 + 160 + i0);
      w30=fmaf(h,wa.x,w30); w31=fmaf(h,wa.y,w31); w32=fmaf(h,wa.z,w32); w33=fmaf(h,wa.w,w33);
      w40=fmaf(h,wb.x,w40); w41=fmaf(h,wb.y,w41); w42=fmaf(h,wb.z,w42); w43=fmaf(h,wb.w,w43);
    }
    float w3a[4] = {w30,w31,w32,w33};
    float w4a[4] = {w40,w41,w42,w43};
    #pragma unroll
    for (int u=0;u<4;u++){
      int i = i0+u;
      float vx=vrow[3*i+0], vy=vrow[3*i+1], vz=vrow[3*i+2];
      float dv = vx*sx + vy*sy + vz*sz;
      // 0.018042... = 0.03125 / sqrt(3)
      atomicAdd(asr+64+i, 0.018042195912175807f*w4a[u]*dv);
      float m3 = 0.03125f*w3a[u];
      atomicAdd(avr+(64+i)*3+0, m3*vx);
      atomicAdd(avr+(64+i)*3+1, m3*vy);
      atomicAdd(avr+(64+i)*3+2, m3*vz);
    }
  }
}

// ---------------- per-layer output transform: o_s, o_v, gating ----------------
__global__ void k_out(const float* __restrict__ a_s, const float* __restrict__ a_v,
                      const float* __restrict__ scs, const float* __restrict__ scv,
                      const float* __restrict__ W2s, const float* __restrict__ W2v,
                      float* __restrict__ s_out, float* __restrict__ v_out){
  __shared__ float las[2][96];
  __shared__ float lav[2][288];
  __shared__ float los[2][96];
  int tid = threadIdx.x;
  int j = tid>>7, t = tid&127;
  int n = blockIdx.x*2 + j;    // exact: 10000*2 = 20000
  for (int i=t;i<96;i+=128)  las[j][i]=a_s[(size_t)n*96+i];
  for (int i=t;i<288;i+=128) lav[j][i]=a_v[(size_t)n*288+i];
  __syncthreads();
  if (t<96){
    float acc=0.0f;
    #pragma unroll 8
    for (int i=0;i<96;i++) acc += las[j][i]*W2s[i*96+t];
    los[j][t] = acc*0.10206207261596575f + scs[(size_t)n*96+t];
  }
  __syncthreads();
  if (t<64) s_out[(size_t)n*64+t] = silu_f(los[j][t]);
  if (t<96){
    int op=t/3, c=t-3*op;
    float acc=0.0f;
    #pragma unroll 8
    for (int i=0;i<96;i++) acc += lav[j][i*3+c]*W2v[i*32+op];
    float ov = acc*0.10206207261596575f + scv[(size_t)n*96+t];
    float g = silu_f(los[j][64+op]);
    v_out[(size_t)n*96+t] = ov*g;
  }
}

// ---------------- final heads: energy + mags ----------------
__global__ void k_final(const float* __restrict__ s, const float* __restrict__ nodes,
                        const int* __restrict__ n_node,
                        const float* __restrict__ Wen1, const float* __restrict__ Wen2,
                        const float* __restrict__ Wm1, const float* __restrict__ Wm2,
                        const float* __restrict__ scale_occ, const float* __restrict__ shift_occ,
                        const float* __restrict__ escale, const float* __restrict__ eshift,
                        float* __restrict__ out){
  __shared__ float eacc[NG];
  __shared__ int goff[NG+1];
  int tid = threadIdx.x;
  if (tid < NG) eacc[tid] = 0.0f;
  if (tid == 0){
    int c = 0; goff[0] = 0;
    for (int g=0; g<NG; g++){ c += n_node[g]; goff[g+1] = c; }
  }
  __syncthreads();
  int n = blockIdx.x*256 + tid;
  if (n < NN){
    float sv[64];
    #pragma unroll
    for (int i=0;i<64;i++) sv[i]=s[(size_t)n*64+i];
    float en=0.0f, m0=0.0f, m1=0.0f;
    #pragma unroll 1
    for (int jj=0;jj<32;jj++){
      float he=0.0f, hm=0.0f;
      #pragma unroll
      for (int i=0;i<64;i++){
        he = fmaf(sv[i], Wen1[i*32+jj], he);
        hm = fmaf(sv[i], Wm1[i*32+jj], hm);
      }
      he *= 0.125f; hm *= 0.125f;
      en = fmaf(he, Wen2[jj], en);
      m0 = fmaf(hm, Wm2[jj*2+0], m0);
      m1 = fmaf(hm, Wm2[jj*2+1], m1);
    }
    const float INVS32 = 0.17677669529663687f;
    en *= INVS32; m0 *= INVS32; m1 *= INVS32;
    en = escale[0]*en + eshift[0];
    int g = 0;
    for (int gg=0; gg<NG; gg++) if (n >= goff[gg+1]) g = gg+1;
    atomicAdd(&eacc[g], en);
    float nx=nodes[n*4+0], ny=nodes[n*4+1], nz=nodes[n*4+2];
    float sc0 = nx*scale_occ[0] + ny*scale_occ[2] + nz*scale_occ[4];
    float sc1 = nx*scale_occ[1] + ny*scale_occ[3] + nz*scale_occ[5];
    float sf0 = nx*shift_occ[0] + ny*shift_occ[2] + nz*shift_occ[4];
    float sf1 = nx*shift_occ[1] + ny*shift_occ[3] + nz*shift_occ[5];
    out[16 + n*2 + 0] = sc0*m0 + sf0;
    out[16 + n*2 + 1] = sc1*m1 + sf1;
  }
  __syncthreads();
  if (tid < NG) atomicAdd(&out[tid], eacc[tid]);
}

extern "C" void kernel_launch(void* const* d_in, const int* in_sizes, int n_in,
                              void* d_out, int out_size, void* d_ws, size_t ws_size,
                              hipStream_t stream){
  const float* nodes   = (const float*)d_in[0];
  const float* dR      = (const float*)d_in[1];
  const int*  senders  = (const int*)d_in[2];
  const int*  receivers= (const int*)d_in[3];
  const int*  n_node   = (const int*)d_in[4];
  const float* W_embed = (const float*)d_in[5];
  const float* W_sc_s  = (const float*)d_in[6];
  const float* W_sc_v  = (const float*)d_in[7];
  const float* W_l1_s  = (const float*)d_in[8];
  const float* W_l1_v  = (const float*)d_in[9];
  const float* Wr0     = (const float*)d_in[10];
  const float* Wr1     = (const float*)d_in[11];
  const float* Wr2     = (const float*)d_in[12];
  const float* W_l2_s  = (const float*)d_in[13];
  const float* W_l2_v  = (const float*)d_in[14];
  const float* W_en1   = (const float*)d_in[15];
  const float* W_en2   = (const float*)d_in[16];
  const float* W_mag1  = (const float*)d_in[17];
  const float* W_mag2  = (const float*)d_in[18];
  const float* scale_occ = (const float*)d_in[19];
  const float* shift_occ = (const float*)d_in[20];
  const float* escale  = (const float*)d_in[21];
  const float* eshift  = (const float*)d_in[22];
  float* out = (float*)d_out;
  float* ws  = (float*)d_ws;

  float* remb = ws;                 // E*8   = 2,560,000
  float* sh1  = ws +  2560000;      // E*3   =   960,000
  float* sA   = ws +  3520000;      // N*64
  float* vA   = ws +  4800000;      // N*96
  float* sB   = ws +  6720000;      // N*64
  float* vB   = ws +  8000000;      // N*96
  float* s1   = ws +  9920000;      // N*64
  float* v1   = ws + 11200000;      // N*96
  float* scs  = ws + 13120000;      // N*96
  float* scv  = ws + 15040000;      // N*96
  float* a_s  = ws + 16960000;      // N*96
  float* a_v  = ws + 18880000;      // N*288  (end: 24,640,000 floats = 98.6 MB)

  hipMemsetAsync(vA, 0, (size_t)NN*96*sizeof(float), stream);   // v starts at zero
  hipMemsetAsync(out, 0, 16*sizeof(float), stream);             // energy accumulators

  k_geom<<<1250, 256, 0, stream>>>(dR, remb, sh1);
  k_embed<<<5000, 256, 0, stream>>>(nodes, W_embed, sA);

  const float* sin_ = sA; const float* vin_ = vA;
  float* sout_ = sB; float* vout_ = vB;
  for (int l=0; l<2; l++){
    k_node<<<5000, 256, 0, stream>>>(sin_, vin_, nodes,
                                     W_l1_s + l*4096, W_l1_v + l*1024,
                                     W_sc_s + l*24576, W_sc_v + l*4096,
                                     s1, v1, scs, scv);
    hipMemsetAsync(a_s, 0, (size_t)NN*384*sizeof(float), stream);  // a_s + a_v contiguous
    k_edge<<<1250, 256, 0, stream>>>(remb, sh1, senders, receivers, s1, v1,
                                     Wr0 + l*512, Wr1 + l*4096, Wr2 + l*12288,
                                     a_s, a_v);
    k_out<<<10000, 256, 0, stream>>>(a_s, a_v, scs, scv,
                                     W_l2_s + l*9216, W_l2_v + l*3072,
                                     sout_, vout_);
    const float* ts = sin_; sin_ = sout_; sout_ = (float*)ts;
    const float* tv = vin_; vin_ = vout_; vout_ = (float*)tv;
  }
  k_final<<<79, 256, 0, stream>>>(sin_, nodes, n_node, W_en1, W_en2, W_mag1, W_mag2,
                                  scale_occ, shift_occ, escale, eshift, out);
}

// Round 2
// 13111.423 us; speedup vs baseline: 1.0029x; 1.0029x over previous
//
#include <hip/hip_runtime.h>
#include <math.h>

#define NN 20000
#define NE 320000
#define NG 16

__device__ __forceinline__ float silu_f(float x){ return x / (1.0f + __expf(-x)); }

// ---------------- geometry: bessel embedding + spherical harmonics ----------------
__global__ void k_geom(const float* __restrict__ dR,
                       float* __restrict__ remb, float* __restrict__ sh1){
  int e = blockIdx.x*256 + threadIdx.x;
  if (e >= NE) return;
  float x = dR[3*e+0], y = dR[3*e+1], z = dR[3*e+2];
  float r = sqrtf(x*x + y*y + z*z);
  float rs = fmaxf(r, 1e-6f);
  float inv = 1.0f / rs;
  const float SQ3 = 1.7320508075688772f;
  sh1[3*e+0] = SQ3 * x * inv;
  sh1[3*e+1] = SQ3 * y * inv;
  sh1[3*e+2] = SQ3 * z * inv;
  float env;
  if (r < 3.5f) env = 1.0f;
  else if (r > 4.0f) env = 0.0f;
  else {
    float t = (r - 3.5f) * 2.0f;
    env = 0.5f * (cosf(3.14159265358979323846f * t) + 1.0f);
  }
  float c = 0.7071067811865476f * inv * env;   // sqrt(2/RMAX) / r_safe * env
  #pragma unroll
  for (int k=0;k<8;k++){
    float arg = (float)(k+1) * 0.7853981633974483f * rs;  // n*pi*r/RMAX
    remb[8*e+k] = c * sinf(arg);
  }
}

// ---------------- node embedding: s = nodes @ W_embed / sqrt(NEL) ----------------
__global__ void k_embed(const float* __restrict__ nodes, const float* __restrict__ W,
                        float* __restrict__ s){
  int idx = blockIdx.x*256 + threadIdx.x;   // N*64 exact
  int n = idx>>6, o = idx&63;
  float a = nodes[n*4+0]*W[o] + nodes[n*4+1]*W[64+o]
          + nodes[n*4+2]*W[128+o] + nodes[n*4+3]*W[192+o];
  s[idx] = 0.5f*a;
}

// ---------------- counting sort of edges by receiver ----------------
__global__ void k_hist(const int* __restrict__ receivers, int* __restrict__ cnt){
  int e = blockIdx.x*256 + threadIdx.x;
  if (e < NE) atomicAdd(&cnt[receivers[e]], 1);
}

__global__ void k_scan(const int* __restrict__ cnt, int* __restrict__ row, int* __restrict__ cur){
  __shared__ int lsum[1024];
  int t = threadIdx.x;
  int base = t*20;
  int local[20];
  int s = 0;
  #pragma unroll
  for (int i=0;i<20;i++){
    int idx = base+i;
    int v = (idx<NN) ? cnt[idx] : 0;
    local[i] = s; s += v;
  }
  lsum[t] = s; __syncthreads();
  for (int off=1; off<1024; off<<=1){
    int v = (t>=off) ? lsum[t-off] : 0;
    __syncthreads();
    lsum[t] += v;
    __syncthreads();
  }
  int pre = (t>0) ? lsum[t-1] : 0;
  #pragma unroll
  for (int i=0;i<20;i++){
    int idx = base+i;
    if (idx<NN){ int r = pre+local[i]; row[idx]=r; cur[idx]=r; }
  }
  if (t==1023) row[NN] = lsum[1023];
}

__global__ void k_scatter(const int* __restrict__ receivers, int* __restrict__ cur,
                          int* __restrict__ perm, int* __restrict__ rank){
  int e = blockIdx.x*256 + threadIdx.x;
  if (e < NE){
    int d = receivers[e];
    int p = atomicAdd(&cur[d], 1);
    perm[p] = e;
    rank[e] = p;
  }
}

// ---------------- per-layer node linears: s1, v1, sc_s, sc_v ----------------
__global__ void k_node(const float* __restrict__ s, const float* __restrict__ v,
                       const float* __restrict__ attrs,
                       const float* __restrict__ W1s, const float* __restrict__ W1v,
                       const float* __restrict__ Wscs, const float* __restrict__ Wscv,
                       float* __restrict__ s1, float* __restrict__ v1,
                       float* __restrict__ scs, float* __restrict__ scv){
  __shared__ float ls[4][64];
  __shared__ float lv[4][96];
  __shared__ float la[4][4];
  int tid = threadIdx.x;
  int nb = blockIdx.x*4;
  {
    int j = tid>>6, q = tid&63;
    ls[j][q] = s[(nb+j)*64+q];
  }
  for (int i=tid;i<384;i+=256){
    int j = i/96, q = i-96*j;
    lv[j][q] = v[(nb+j)*96+q];
  }
  if (tid<16) la[tid>>2][tid&3] = attrs[(nb+(tid>>2))*4 + (tid&3)];
  __syncthreads();
  int j = tid>>6, q = tid&63;
  int n = nb+j;
  {
    float acc=0.0f;
    #pragma unroll 8
    for (int i=0;i<64;i++) acc += ls[j][i]*W1s[i*64+q];
    s1[n*64+q] = acc*0.125f;
  }
  #pragma unroll 1
  for (int o=q;o<96;o+=64){
    float acc=0.0f;
    #pragma unroll 4
    for (int i=0;i<64;i++){
      float sv = ls[j][i];
      const float* wp = Wscs + (i*4)*96 + o;
      acc += sv*(la[j][0]*wp[0] + la[j][1]*wp[96] + la[j][2]*wp[192] + la[j][3]*wp[288]);
    }
    scs[n*96+o] = acc*0.0625f;
  }
  #pragma unroll 1
  for (int f=q;f<96;f+=64){
    int op=f/3, c=f-3*op;
    float acc=0.0f;
    #pragma unroll 8
    for (int i=0;i<32;i++) acc += lv[j][i*3+c]*W1v[i*32+op];
    v1[n*96+f] = acc*0.17677669529663687f;
  }
  #pragma unroll 1
  for (int f=q;f<96;f+=64){
    int op=f/3, c=f-3*op;
    float acc=0.0f;
    #pragma unroll 4
    for (int i=0;i<32;i++){
      float vv = lv[j][i*3+c];
      const float* wp = Wscv + (i*4)*32 + op;
      acc += vv*(la[j][0]*wp[0] + la[j][1]*wp[32] + la[j][2]*wp[64] + la[j][3]*wp[96]);
    }
    scv[n*96+f] = acc*0.08838834764831845f;
  }
}

// ---------------- per-layer edge kernel (fast path): radial MLP -> w buffer ----------------
__launch_bounds__(256, 2)
__global__ void k_edgew(const float* __restrict__ remb,
                        const int* __restrict__ rank,
                        const float* __restrict__ R0, const float* __restrict__ R1,
                        const float* __restrict__ R2,
                        float* __restrict__ wbuf){
  __shared__ __align__(16) float lR1[64*64];    // 16 KB
  __shared__ __align__(16) float lR2[64*192];   // 48 KB
  int tid = threadIdx.x;
  for (int i=tid;i<4096;i+=256)  lR1[i]=R1[i];
  for (int i=tid;i<12288;i+=256) lR2[i]=R2[i];
  __syncthreads();
  int e = blockIdx.x*256 + tid;   // exact: 1250*256 = 320000
  float rb[8];
  #pragma unroll
  for (int k=0;k<8;k++) rb[k]=remb[8*e+k];
  float h1[64];
  #pragma unroll
  for (int j=0;j<64;j+=4){
    float a0=0,a1=0,a2=0,a3=0;
    #pragma unroll
    for (int k=0;k<8;k++){
      float r = rb[k];
      const float* wp = R0 + k*64 + j;   // uniform address -> scalar loads
      a0 = fmaf(r, wp[0], a0); a1 = fmaf(r, wp[1], a1);
      a2 = fmaf(r, wp[2], a2); a3 = fmaf(r, wp[3], a3);
    }
    h1[j+0]=silu_f(a0*0.3535533905932738f);
    h1[j+1]=silu_f(a1*0.3535533905932738f);
    h1[j+2]=silu_f(a2*0.3535533905932738f);
    h1[j+3]=silu_f(a3*0.3535533905932738f);
  }
  float h2[64];
  #pragma unroll
  for (int j=0;j<64;j+=4){
    float a0=0,a1=0,a2=0,a3=0;
    #pragma unroll
    for (int k=0;k<64;k++){
      float h = h1[k];
      float4 w4 = *(const float4*)(lR1 + k*64 + j);
      a0 = fmaf(h,w4.x,a0); a1 = fmaf(h,w4.y,a1);
      a2 = fmaf(h,w4.z,a2); a3 = fmaf(h,w4.w,a3);
    }
    h2[j+0]=silu_f(a0*0.125f);
    h2[j+1]=silu_f(a1*0.125f);
    h2[j+2]=silu_f(a2*0.125f);
    h2[j+3]=silu_f(a3*0.125f);
  }
  size_t rowo = (size_t)rank[e]*192;
  // w1 [0:64], w2 [64:128]
  #pragma unroll 1
  for (int o=0;o<64;o+=4){
    float w10=0,w11=0,w12=0,w13=0, w20=0,w21=0,w22=0,w23=0;
    #pragma unroll
    for (int k=0;k<64;k++){
      float h = h2[k];
      float4 wa = *(const float4*)(lR2 + k*192 + o);
      float4 wb = *(const float4*)(lR2 + k*192 + 64 + o);
      w10=fmaf(h,wa.x,w10); w11=fmaf(h,wa.y,w11); w12=fmaf(h,wa.z,w12); w13=fmaf(h,wa.w,w13);
      w20=fmaf(h,wb.x,w20); w21=fmaf(h,wb.y,w21); w22=fmaf(h,wb.z,w22); w23=fmaf(h,wb.w,w23);
    }
    *(float4*)(wbuf + rowo + o)      = make_float4(w10,w11,w12,w13);
    *(float4*)(wbuf + rowo + 64 + o) = make_float4(w20,w21,w22,w23);
  }
  // w3 [128:160], w4 [160:192]
  #pragma unroll 1
  for (int i0=0;i0<32;i0+=4){
    float w30=0,w31=0,w32=0,w33=0, w40=0,w41=0,w42=0,w43=0;
    #pragma unroll
    for (int k=0;k<64;k++){
      float h = h2[k];
      float4 wa = *(const float4*)(lR2 + k*192 + 128 + i0);
      float4 wb = *(const float4*)(lR2 + k*192 + 160 + i0);
      w30=fmaf(h,wa.x,w30); w31=fmaf(h,wa.y,w31); w32=fmaf(h,wa.z,w32); w33=fmaf(h,wa.w,w33);
      w40=fmaf(h,wb.x,w40); w41=fmaf(h,wb.y,w41); w42=fmaf(h,wb.z,w42); w43=fmaf(h,wb.w,w43);
    }
    *(float4*)(wbuf + rowo + 128 + i0) = make_float4(w30,w31,w32,w33);
    *(float4*)(wbuf + rowo + 160 + i0) = make_float4(w40,w41,w42,w43);
  }
}

// ---------------- per-layer gather (fast path): sorted pull, no atomics ----------------
__global__ void k_gather(const float* __restrict__ wbuf, const int* __restrict__ perm,
                         const int* __restrict__ row, const int* __restrict__ senders,
                         const float* __restrict__ sh1,
                         const float* __restrict__ s1, const float* __restrict__ v1,
                         float* __restrict__ a_s, float* __restrict__ a_v){
  int n = blockIdx.x;
  int t = threadIdx.x;
  int p0 = row[n], p1 = row[n+1];
  float acc = 0.0f;
  if (t < 64){
    for (int p=p0;p<p1;p++){
      int e = perm[p]; int src = senders[e];
      acc = fmaf(wbuf[(size_t)p*192 + t], s1[(size_t)src*64 + t], acc);
    }
    a_s[(size_t)n*96 + t] = 0.03125f*acc;           // (1/8)*(1/sqrt(16))
  } else if (t < 96){
    int i = t-64;
    for (int p=p0;p<p1;p++){
      int e = perm[p]; int src = senders[e];
      float sx=sh1[3*e+0], sy=sh1[3*e+1], sz=sh1[3*e+2];
      const float* vr = v1 + (size_t)src*96 + 3*i;
      float dv = vr[0]*sx + vr[1]*sy + vr[2]*sz;
      acc = fmaf(wbuf[(size_t)p*192 + 160 + i], dv, acc);
    }
    a_s[(size_t)n*96 + t] = 0.018042195912175807f*acc;  // 0.03125/sqrt(3)
  } else {
    int idx = t-96; int o = idx/3; int c = idx-3*o;
    if (o < 64){
      for (int p=p0;p<p1;p++){
        int e = perm[p]; int src = senders[e];
        acc = fmaf(wbuf[(size_t)p*192 + 64 + o] * s1[(size_t)src*64 + o], sh1[3*e+c], acc);
      }
    } else {
      int i = o-64;
      for (int p=p0;p<p1;p++){
        int e = perm[p]; int src = senders[e];
        acc = fmaf(wbuf[(size_t)p*192 + 128 + i], v1[(size_t)src*96 + 3*i + c], acc);
      }
    }
    a_v[(size_t)n*288 + idx] = 0.03125f*acc;
  }
}

// ---------------- per-layer edge kernel (fallback path): atomics ----------------
__launch_bounds__(256, 2)
__global__ void k_edge(const float* __restrict__ remb, const float* __restrict__ sh1,
                       const int* __restrict__ senders, const int* __restrict__ receivers,
                       const float* __restrict__ s1, const float* __restrict__ v1,
                       const float* __restrict__ R0, const float* __restrict__ R1,
                       const float* __restrict__ R2,
                       float* __restrict__ a_s, float* __restrict__ a_v){
  __shared__ __align__(16) float lR1[64*64];
  __shared__ __align__(16) float lR2[64*192];
  int tid = threadIdx.x;
  for (int i=tid;i<4096;i+=256)  lR1[i]=R1[i];
  for (int i=tid;i<12288;i+=256) lR2[i]=R2[i];
  __syncthreads();
  int e = blockIdx.x*256 + tid;
  float rb[8];
  #pragma unroll
  for (int k=0;k<8;k++) rb[k]=remb[8*e+k];
  float h1[64];
  #pragma unroll
  for (int j=0;j<64;j+=4){
    float a0=0,a1=0,a2=0,a3=0;
    #pragma unroll
    for (int k=0;k<8;k++){
      float r = rb[k];
      const float* wp = R0 + k*64 + j;
      a0 = fmaf(r, wp[0], a0); a1 = fmaf(r, wp[1], a1);
      a2 = fmaf(r, wp[2], a2); a3 = fmaf(r, wp[3], a3);
    }
    h1[j+0]=silu_f(a0*0.3535533905932738f);
    h1[j+1]=silu_f(a1*0.3535533905932738f);
    h1[j+2]=silu_f(a2*0.3535533905932738f);
    h1[j+3]=silu_f(a3*0.3535533905932738f);
  }
  float h2[64];
  #pragma unroll
  for (int j=0;j<64;j+=4){
    float a0=0,a1=0,a2=0,a3=0;
    #pragma unroll
    for (int k=0;k<64;k++){
      float h = h1[k];
      float4 w4 = *(const float4*)(lR1 + k*64 + j);
      a0 = fmaf(h,w4.x,a0); a1 = fmaf(h,w4.y,a1);
      a2 = fmaf(h,w4.z,a2); a3 = fmaf(h,w4.w,a3);
    }
    h2[j+0]=silu_f(a0*0.125f);
    h2[j+1]=silu_f(a1*0.125f);
    h2[j+2]=silu_f(a2*0.125f);
    h2[j+3]=silu_f(a3*0.125f);
  }
  int src = senders[e], dst = receivers[e];
  float sx=sh1[3*e+0], sy=sh1[3*e+1], sz=sh1[3*e+2];
  const float* srow = s1 + (size_t)src*64;
  const float* vrow = v1 + (size_t)src*96;
  float* asr = a_s + (size_t)dst*96;
  float* avr = a_v + (size_t)dst*288;
  #pragma unroll 1
  for (int o=0;o<64;o+=4){
    float w10=0,w11=0,w12=0,w13=0, w20=0,w21=0,w22=0,w23=0;
    #pragma unroll
    for (int k=0;k<64;k++){
      float h = h2[k];
      float4 wa = *(const float4*)(lR2 + k*192 + o);
      float4 wb = *(const float4*)(lR2 + k*192 + 64 + o);
      w10=fmaf(h,wa.x,w10); w11=fmaf(h,wa.y,w11); w12=fmaf(h,wa.z,w12); w13=fmaf(h,wa.w,w13);
      w20=fmaf(h,wb.x,w20); w21=fmaf(h,wb.y,w21); w22=fmaf(h,wb.z,w22); w23=fmaf(h,wb.w,w23);
    }
    float4 se4 = *(const float4*)(srow + o);
    float sev[4] = {se4.x, se4.y, se4.z, se4.w};
    float w1a[4] = {w10,w11,w12,w13};
    float w2a[4] = {w20,w21,w22,w23};
    #pragma unroll
    for (int u=0;u<4;u++){
      atomicAdd(asr+o+u, 0.03125f*w1a[u]*sev[u]);
      float m = 0.03125f*w2a[u]*sev[u];
      atomicAdd(avr+(o+u)*3+0, m*sx);
      atomicAdd(avr+(o+u)*3+1, m*sy);
      atomicAdd(avr+(o+u)*3+2, m*sz);
    }
  }
  #pragma unroll 1
  for (int i0=0;i0<32;i0+=4){
    float w30=0,w31=0,w32=0,w33=0, w40=0,w41=0,w42=0,w43=0;
    #pragma unroll
    for (int k=0;k<64;k++){
      float h = h2[k];
      float4 wa = *(const float4*)(lR2 + k*192 + 128 + i0);
      float4 wb = *(const float4*)(lR2 + k*192 + 160 + i0);
      w30=fmaf(h,wa.x,w30); w31=fmaf(h,wa.y,w31); w32=fmaf(h,wa.z,w32); w33=fmaf(h,wa.w,w33);
      w40=fmaf(h,wb.x,w40); w41=fmaf(h,wb.y,w41); w42=fmaf(h,wb.z,w42); w43=fmaf(h,wb.w,w43);
    }
    float w3a[4] = {w30,w31,w32,w33};
    float w4a[4] = {w40,w41,w42,w43};
    #pragma unroll
    for (int u=0;u<4;u++){
      int i = i0+u;
      float vx=vrow[3*i+0], vy=vrow[3*i+1], vz=vrow[3*i+2];
      float dv = vx*sx + vy*sy + vz*sz;
      atomicAdd(asr+64+i, 0.018042195912175807f*w4a[u]*dv);
      float m3 = 0.03125f*w3a[u];
      atomicAdd(avr+(64+i)*3+0, m3*vx);
      atomicAdd(avr+(64+i)*3+1, m3*vy);
      atomicAdd(avr+(64+i)*3+2, m3*vz);
    }
  }
}

// ---------------- per-layer output transform: o_s, o_v, gating ----------------
__global__ void k_out(const float* __restrict__ a_s, const float* __restrict__ a_v,
                      const float* __restrict__ scs, const float* __restrict__ scv,
                      const float* __restrict__ W2s, const float* __restrict__ W2v,
                      float* __restrict__ s_out, float* __restrict__ v_out){
  __shared__ float las[2][96];
  __shared__ float lav[2][288];
  __shared__ float los[2][96];
  int tid = threadIdx.x;
  int j = tid>>7, t = tid&127;
  int n = blockIdx.x*2 + j;
  for (int i=t;i<96;i+=128)  las[j][i]=a_s[(size_t)n*96+i];
  for (int i=t;i<288;i+=128) lav[j][i]=a_v[(size_t)n*288+i];
  __syncthreads();
  if (t<96){
    float acc=0.0f;
    #pragma unroll 8
    for (int i=0;i<96;i++) acc += las[j][i]*W2s[i*96+t];
    los[j][t] = acc*0.10206207261596575f + scs[(size_t)n*96+t];
  }
  __syncthreads();
  if (t<64) s_out[(size_t)n*64+t] = silu_f(los[j][t]);
  if (t<96){
    int op=t/3, c=t-3*op;
    float acc=0.0f;
    #pragma unroll 8
    for (int i=0;i<96;i++) acc += lav[j][i*3+c]*W2v[i*32+op];
    float ov = acc*0.10206207261596575f + scv[(size_t)n*96+t];
    float g = silu_f(los[j][64+op]);
    v_out[(size_t)n*96+t] = ov*g;
  }
}

// ---------------- final heads: energy + mags ----------------
__global__ void k_final(const float* __restrict__ s, const float* __restrict__ nodes,
                        const int* __restrict__ n_node,
                        const float* __restrict__ Wen1, const float* __restrict__ Wen2,
                        const float* __restrict__ Wm1, const float* __restrict__ Wm2,
                        const float* __restrict__ scale_occ, const float* __restrict__ shift_occ,
                        const float* __restrict__ escale, const float* __restrict__ eshift,
                        float* __restrict__ out){
  __shared__ float eacc[NG];
  __shared__ int goff[NG+1];
  int tid = threadIdx.x;
  if (tid < NG) eacc[tid] = 0.0f;
  if (tid == 0){
    int c = 0; goff[0] = 0;
    for (int g=0; g<NG; g++){ c += n_node[g]; goff[g+1] = c; }
  }
  __syncthreads();
  int n = blockIdx.x*256 + tid;
  if (n < NN){
    float sv[64];
    #pragma unroll
    for (int i=0;i<64;i++) sv[i]=s[(size_t)n*64+i];
    float en=0.0f, m0=0.0f, m1=0.0f;
    #pragma unroll 1
    for (int jj=0;jj<32;jj++){
      float he=0.0f, hm=0.0f;
      #pragma unroll
      for (int i=0;i<64;i++){
        he = fmaf(sv[i], Wen1[i*32+jj], he);
        hm = fmaf(sv[i], Wm1[i*32+jj], hm);
      }
      he *= 0.125f; hm *= 0.125f;
      en = fmaf(he, Wen2[jj], en);
      m0 = fmaf(hm, Wm2[jj*2+0], m0);
      m1 = fmaf(hm, Wm2[jj*2+1], m1);
    }
    const float INVS32 = 0.17677669529663687f;
    en *= INVS32; m0 *= INVS32; m1 *= INVS32;
    en = escale[0]*en + eshift[0];
    int g = 0;
    for (int gg=0; gg<NG; gg++) if (n >= goff[gg+1]) g = gg+1;
    atomicAdd(&eacc[g], en);
    float nx=nodes[n*4+0], ny=nodes[n*4+1], nz=nodes[n*4+2];
    float sc0 = nx*scale_occ[0] + ny*scale_occ[2] + nz*scale_occ[4];
    float sc1 = nx*scale_occ[1] + ny*scale_occ[3] + nz*scale_occ[5];
    float sf0 = nx*shift_occ[0] + ny*shift_occ[2] + nz*shift_occ[4];
    float sf1 = nx*shift_occ[1] + ny*shift_occ[3] + nz*shift_occ[5];
    out[16 + n*2 + 0] = sc0*m0 + sf0;
    out[16 + n*2 + 1] = sc1*m1 + sf1;
  }
  __syncthreads();
  if (tid < NG) atomicAdd(&out[tid], eacc[tid]);
}

extern "C" void kernel_launch(void* const* d_in, const int* in_sizes, int n_in,
                              void* d_out, int out_size, void* d_ws, size_t ws_size,
                              hipStream_t stream){
  const float* nodes   = (const float*)d_in[0];
  const float* dR      = (const float*)d_in[1];
  const int*  senders  = (const int*)d_in[2];
  const int*  receivers= (const int*)d_in[3];
  const int*  n_node   = (const int*)d_in[4];
  const float* W_embed = (const float*)d_in[5];
  const float* W_sc_s  = (const float*)d_in[6];
  const float* W_sc_v  = (const float*)d_in[7];
  const float* W_l1_s  = (const float*)d_in[8];
  const float* W_l1_v  = (const float*)d_in[9];
  const float* Wr0     = (const float*)d_in[10];
  const float* Wr1     = (const float*)d_in[11];
  const float* Wr2     = (const float*)d_in[12];
  const float* W_l2_s  = (const float*)d_in[13];
  const float* W_l2_v  = (const float*)d_in[14];
  const float* W_en1   = (const float*)d_in[15];
  const float* W_en2   = (const float*)d_in[16];
  const float* W_mag1  = (const float*)d_in[17];
  const float* W_mag2  = (const float*)d_in[18];
  const float* scale_occ = (const float*)d_in[19];
  const float* shift_occ = (const float*)d_in[20];
  const float* escale  = (const float*)d_in[21];
  const float* eshift  = (const float*)d_in[22];
  float* out = (float*)d_out;
  float* ws  = (float*)d_ws;

  float* remb = ws;                 // E*8   = 2,560,000
  float* sh1  = ws +  2560000;      // E*3
  float* sA   = ws +  3520000;      // N*64
  float* vA   = ws +  4800000;      // N*96
  float* sB   = ws +  6720000;      // N*64
  float* vB   = ws +  8000000;      // N*96
  float* s1   = ws +  9920000;      // N*64
  float* v1   = ws + 11200000;      // N*96
  float* scs  = ws + 13120000;      // N*96
  float* scv  = ws + 15040000;      // N*96
  float* a_s  = ws + 16960000;      // N*96
  float* a_v  = ws + 18880000;      // N*288   end: 24,640,000 floats
  // sort + w-buffer region (fast path only)
  int*   cnt  = (int*)(ws + 24640000);   // NN
  int*   row  = (int*)(ws + 24660000);   // NN+1
  int*   cur  = (int*)(ws + 24680008);   // NN
  int*   perm = (int*)(ws + 24700008);   // NE
  int*   rank = (int*)(ws + 25020008);   // NE
  float* wbuf = ws + 25340008;           // NE*192   end: 86,780,008 floats
  const size_t NEED_BYTES = 86780008ull * 4ull;
  const bool fast = (ws_size >= NEED_BYTES);

  hipMemsetAsync(vA, 0, (size_t)NN*96*sizeof(float), stream);   // v starts at zero
  hipMemsetAsync(out, 0, 16*sizeof(float), stream);             // energy accumulators

  k_geom<<<1250, 256, 0, stream>>>(dR, remb, sh1);
  k_embed<<<5000, 256, 0, stream>>>(nodes, W_embed, sA);

  if (fast){
    hipMemsetAsync(cnt, 0, NN*sizeof(int), stream);
    k_hist<<<1250, 256, 0, stream>>>(receivers, cnt);
    k_scan<<<1, 1024, 0, stream>>>(cnt, row, cur);
    k_scatter<<<1250, 256, 0, stream>>>(receivers, cur, perm, rank);
  }

  const float* sin_ = sA; const float* vin_ = vA;
  float* sout_ = sB; float* vout_ = vB;
  for (int l=0; l<2; l++){
    k_node<<<5000, 256, 0, stream>>>(sin_, vin_, nodes,
                                     W_l1_s + l*4096, W_l1_v + l*1024,
                                     W_sc_s + l*24576, W_sc_v + l*4096,
                                     s1, v1, scs, scv);
    if (fast){
      k_edgew<<<1250, 256, 0, stream>>>(remb, rank,
                                        Wr0 + l*512, Wr1 + l*4096, Wr2 + l*12288,
                                        wbuf);
      k_gather<<<20000, 384, 0, stream>>>(wbuf, perm, row, senders, sh1, s1, v1,
                                          a_s, a_v);
    } else {
      hipMemsetAsync(a_s, 0, (size_t)NN*384*sizeof(float), stream);
      k_edge<<<1250, 256, 0, stream>>>(remb, sh1, senders, receivers, s1, v1,
                                       Wr0 + l*512, Wr1 + l*4096, Wr2 + l*12288,
                                       a_s, a_v);
    }
    k_out<<<10000, 256, 0, stream>>>(a_s, a_v, scs, scv,
                                     W_l2_s + l*9216, W_l2_v + l*3072,
                                     sout_, vout_);
    const float* ts = sin_; sin_ = sout_; sout_ = (float*)ts;
    const float* tv = vin_; vin_ = vout_; vout_ = (float*)tv;
  }
  k_final<<<79, 256, 0, stream>>>(sin_, nodes, n_node, W_en1, W_en2, W_mag1, W_mag2,
                                  scale_occ, shift_occ, escale, eshift, out);
}

// Round 3
// 1670.706 us; speedup vs baseline: 7.8705x; 7.8478x over previous
//
#include <hip/hip_runtime.h>
#include <math.h>

#define NN 20000
#define NE 320000
#define NG 16

__device__ __forceinline__ float silu_f(float x){ return x / (1.0f + __expf(-x)); }

// recompute bessel basis from dR (identical math/constants to k_geom of rounds 0-1)
__device__ __forceinline__ void bessel8(const float* __restrict__ dR, int e, float* rb){
  float x = dR[3*e+0], y = dR[3*e+1], z = dR[3*e+2];
  float r = sqrtf(x*x + y*y + z*z);
  float rs = fmaxf(r, 1e-6f);
  float inv = 1.0f / rs;
  float env;
  if (r < 3.5f) env = 1.0f;
  else if (r > 4.0f) env = 0.0f;
  else {
    float t = (r - 3.5f) * 2.0f;
    env = 0.5f * (cosf(3.14159265358979323846f * t) + 1.0f);
  }
  float c = 0.7071067811865476f * inv * env;
  #pragma unroll
  for (int k=0;k<8;k++){
    float arg = (float)(k+1) * 0.7853981633974483f * rs;
    rb[k] = c * sinf(arg);
  }
}

// ---------------- geometry: spherical harmonics only ----------------
__global__ void k_geom(const float* __restrict__ dR, float* __restrict__ sh1){
  int e = blockIdx.x*256 + threadIdx.x;
  if (e >= NE) return;
  float x = dR[3*e+0], y = dR[3*e+1], z = dR[3*e+2];
  float r = sqrtf(x*x + y*y + z*z);
  float inv = 1.0f / fmaxf(r, 1e-6f);
  const float SQ3 = 1.7320508075688772f;
  sh1[3*e+0] = SQ3 * x * inv;
  sh1[3*e+1] = SQ3 * y * inv;
  sh1[3*e+2] = SQ3 * z * inv;
}

// ---------------- node embedding ----------------
__global__ void k_embed(const float* __restrict__ nodes, const float* __restrict__ W,
                        float* __restrict__ s){
  int idx = blockIdx.x*256 + threadIdx.x;   // N*64 exact
  int n = idx>>6, o = idx&63;
  float a = nodes[n*4+0]*W[o] + nodes[n*4+1]*W[64+o]
          + nodes[n*4+2]*W[128+o] + nodes[n*4+3]*W[192+o];
  s[idx] = 0.5f*a;
}

// ---------------- counting sort of edges by receiver ----------------
__global__ void k_hist(const int* __restrict__ receivers, int* __restrict__ cnt){
  int e = blockIdx.x*256 + threadIdx.x;
  if (e < NE) atomicAdd(&cnt[receivers[e]], 1);
}

__global__ void k_scan(const int* __restrict__ cnt, int* __restrict__ row, int* __restrict__ cur){
  __shared__ int lsum[1024];
  int t = threadIdx.x;
  int base = t*20;
  int local[20];
  int s = 0;
  #pragma unroll
  for (int i=0;i<20;i++){
    int idx = base+i;
    int v = (idx<NN) ? cnt[idx] : 0;
    local[i] = s; s += v;
  }
  lsum[t] = s; __syncthreads();
  for (int off=1; off<1024; off<<=1){
    int v = (t>=off) ? lsum[t-off] : 0;
    __syncthreads();
    lsum[t] += v;
    __syncthreads();
  }
  int pre = (t>0) ? lsum[t-1] : 0;
  #pragma unroll
  for (int i=0;i<20;i++){
    int idx = base+i;
    if (idx<NN){ int r = pre+local[i]; row[idx]=r; cur[idx]=r; }
  }
  if (t==1023) row[NN] = lsum[1023];
}

__global__ void k_scatter(const int* __restrict__ receivers, int* __restrict__ cur,
                          int* __restrict__ perm){
  int e = blockIdx.x*256 + threadIdx.x;
  if (e < NE){
    int d = receivers[e];
    int p = atomicAdd(&cur[d], 1);
    perm[p] = e;
  }
}

// ---------------- per-layer node linears: s1, v1, sc_s, sc_v ----------------
__global__ void k_node(const float* __restrict__ s, const float* __restrict__ v,
                       const float* __restrict__ attrs,
                       const float* __restrict__ W1s, const float* __restrict__ W1v,
                       const float* __restrict__ Wscs, const float* __restrict__ Wscv,
                       float* __restrict__ s1, float* __restrict__ v1,
                       float* __restrict__ scs, float* __restrict__ scv){
  __shared__ float ls[4][64];
  __shared__ float lv[4][96];
  __shared__ float la[4][4];
  int tid = threadIdx.x;
  int nb = blockIdx.x*4;
  {
    int j = tid>>6, q = tid&63;
    ls[j][q] = s[(nb+j)*64+q];
  }
  for (int i=tid;i<384;i+=256){
    int j = i/96, q = i-96*j;
    lv[j][q] = v[(nb+j)*96+q];
  }
  if (tid<16) la[tid>>2][tid&3] = attrs[(nb+(tid>>2))*4 + (tid&3)];
  __syncthreads();
  int j = tid>>6, q = tid&63;
  int n = nb+j;
  {
    float acc=0.0f;
    #pragma unroll 8
    for (int i=0;i<64;i++) acc += ls[j][i]*W1s[i*64+q];
    s1[n*64+q] = acc*0.125f;
  }
  #pragma unroll 1
  for (int o=q;o<96;o+=64){
    float acc=0.0f;
    #pragma unroll 4
    for (int i=0;i<64;i++){
      float sv = ls[j][i];
      const float* wp = Wscs + (i*4)*96 + o;
      acc += sv*(la[j][0]*wp[0] + la[j][1]*wp[96] + la[j][2]*wp[192] + la[j][3]*wp[288]);
    }
    scs[n*96+o] = acc*0.0625f;
  }
  #pragma unroll 1
  for (int f=q;f<96;f+=64){
    int op=f/3, c=f-3*op;
    float acc=0.0f;
    #pragma unroll 8
    for (int i=0;i<32;i++) acc += lv[j][i*3+c]*W1v[i*32+op];
    v1[n*96+f] = acc*0.17677669529663687f;
  }
  #pragma unroll 1
  for (int f=q;f<96;f+=64){
    int op=f/3, c=f-3*op;
    float acc=0.0f;
    #pragma unroll 4
    for (int i=0;i<32;i++){
      float vv = lv[j][i*3+c];
      const float* wp = Wscv + (i*4)*32 + op;
      acc += vv*(la[j][0]*wp[0] + la[j][1]*wp[32] + la[j][2]*wp[64] + la[j][3]*wp[96]);
    }
    scv[n*96+f] = acc*0.08838834764831845f;
  }
}

// ---------------- edge MLP over sorted ranks [row[n0], row[n1]) -> wbuf chunk ----------------
__launch_bounds__(256, 2)
__global__ void k_edgew(const float* __restrict__ dR, const int* __restrict__ perm,
                        const int* __restrict__ row, int n0, int n1, int cap,
                        const float* __restrict__ R0, const float* __restrict__ R1,
                        const float* __restrict__ R2,
                        float* __restrict__ wbuf){
  __shared__ __align__(16) float lR1[64*64];    // 16 KB
  __shared__ __align__(16) float lR2[64*192];   // 48 KB
  int tid = threadIdx.x;
  for (int i=tid;i<4096;i+=256)  lR1[i]=R1[i];
  for (int i=tid;i<12288;i+=256) lR2[i]=R2[i];
  __syncthreads();
  int p0 = row[n0], p1 = row[n1];
  int idx = blockIdx.x*256 + tid;
  int p = p0 + idx;
  if (idx >= cap || p >= p1) return;
  int e = perm[p];
  float rb[8];
  bessel8(dR, e, rb);
  float h1[64];
  #pragma unroll
  for (int j=0;j<64;j+=4){
    float a0=0,a1=0,a2=0,a3=0;
    #pragma unroll
    for (int k=0;k<8;k++){
      float r = rb[k];
      const float* wp = R0 + k*64 + j;   // uniform address -> scalar loads
      a0 = fmaf(r, wp[0], a0); a1 = fmaf(r, wp[1], a1);
      a2 = fmaf(r, wp[2], a2); a3 = fmaf(r, wp[3], a3);
    }
    h1[j+0]=silu_f(a0*0.3535533905932738f);
    h1[j+1]=silu_f(a1*0.3535533905932738f);
    h1[j+2]=silu_f(a2*0.3535533905932738f);
    h1[j+3]=silu_f(a3*0.3535533905932738f);
  }
  float h2[64];
  #pragma unroll
  for (int j=0;j<64;j+=4){
    float a0=0,a1=0,a2=0,a3=0;
    #pragma unroll
    for (int k=0;k<64;k++){
      float h = h1[k];
      float4 w4 = *(const float4*)(lR1 + k*64 + j);
      a0 = fmaf(h,w4.x,a0); a1 = fmaf(h,w4.y,a1);
      a2 = fmaf(h,w4.z,a2); a3 = fmaf(h,w4.w,a3);
    }
    h2[j+0]=silu_f(a0*0.125f);
    h2[j+1]=silu_f(a1*0.125f);
    h2[j+2]=silu_f(a2*0.125f);
    h2[j+3]=silu_f(a3*0.125f);
  }
  size_t rowo = (size_t)idx*192;
  #pragma unroll 1
  for (int o=0;o<64;o+=4){
    float w10=0,w11=0,w12=0,w13=0, w20=0,w21=0,w22=0,w23=0;
    #pragma unroll
    for (int k=0;k<64;k++){
      float h = h2[k];
      float4 wa = *(const float4*)(lR2 + k*192 + o);
      float4 wb = *(const float4*)(lR2 + k*192 + 64 + o);
      w10=fmaf(h,wa.x,w10); w11=fmaf(h,wa.y,w11); w12=fmaf(h,wa.z,w12); w13=fmaf(h,wa.w,w13);
      w20=fmaf(h,wb.x,w20); w21=fmaf(h,wb.y,w21); w22=fmaf(h,wb.z,w22); w23=fmaf(h,wb.w,w23);
    }
    *(float4*)(wbuf + rowo + o)      = make_float4(w10,w11,w12,w13);
    *(float4*)(wbuf + rowo + 64 + o) = make_float4(w20,w21,w22,w23);
  }
  #pragma unroll 1
  for (int i0=0;i0<32;i0+=4){
    float w30=0,w31=0,w32=0,w33=0, w40=0,w41=0,w42=0,w43=0;
    #pragma unroll
    for (int k=0;k<64;k++){
      float h = h2[k];
      float4 wa = *(const float4*)(lR2 + k*192 + 128 + i0);
      float4 wb = *(const float4*)(lR2 + k*192 + 160 + i0);
      w30=fmaf(h,wa.x,w30); w31=fmaf(h,wa.y,w31); w32=fmaf(h,wa.z,w32); w33=fmaf(h,wa.w,w33);
      w40=fmaf(h,wb.x,w40); w41=fmaf(h,wb.y,w41); w42=fmaf(h,wb.z,w42); w43=fmaf(h,wb.w,w43);
    }
    *(float4*)(wbuf + rowo + 128 + i0) = make_float4(w30,w31,w32,w33);
    *(float4*)(wbuf + rowo + 160 + i0) = make_float4(w40,w41,w42,w43);
  }
}

// ---------------- gather for node chunk [n0, n0+grid): sorted pull, no atomics ----------------
__global__ void k_gather(const float* __restrict__ wbuf, const int* __restrict__ perm,
                         const int* __restrict__ row, const int* __restrict__ senders,
                         const float* __restrict__ sh1,
                         const float* __restrict__ s1, const float* __restrict__ v1,
                         int n0, int cap,
                         float* __restrict__ a_s, float* __restrict__ a_v){
  int n = n0 + blockIdx.x;
  int t = threadIdx.x;
  int pc0 = row[n0];
  int p0 = row[n], p1 = row[n+1];
  int pmax = pc0 + cap; if (p1 > pmax) p1 = pmax;
  float acc = 0.0f;
  if (t < 64){
    for (int p=p0;p<p1;p++){
      int src = senders[perm[p]];
      acc = fmaf(wbuf[(size_t)(p-pc0)*192 + t], s1[(size_t)src*64 + t], acc);
    }
    a_s[(size_t)n*96 + t] = 0.03125f*acc;           // (1/8)*(1/sqrt(16))
  } else if (t < 96){
    int i = t-64;
    for (int p=p0;p<p1;p++){
      int e = perm[p]; int src = senders[e];
      float sx=sh1[3*e+0], sy=sh1[3*e+1], sz=sh1[3*e+2];
      const float* vr = v1 + (size_t)src*96 + 3*i;
      float dv = vr[0]*sx + vr[1]*sy + vr[2]*sz;
      acc = fmaf(wbuf[(size_t)(p-pc0)*192 + 160 + i], dv, acc);
    }
    a_s[(size_t)n*96 + t] = 0.018042195912175807f*acc;  // 0.03125/sqrt(3)
  } else {
    int idx = t-96; int o = idx/3; int c = idx-3*o;
    if (o < 64){
      for (int p=p0;p<p1;p++){
        int e = perm[p]; int src = senders[e];
        acc = fmaf(wbuf[(size_t)(p-pc0)*192 + 64 + o] * s1[(size_t)src*64 + o], sh1[3*e+c], acc);
      }
    } else {
      int i = o-64;
      for (int p=p0;p<p1;p++){
        int e = perm[p]; int src = senders[e];
        acc = fmaf(wbuf[(size_t)(p-pc0)*192 + 128 + i], v1[(size_t)src*96 + 3*i + c], acc);
      }
    }
    a_v[(size_t)n*288 + idx] = 0.03125f*acc;
  }
}

// ---------------- fallback: atomic edge kernel (only if ws too small) ----------------
__launch_bounds__(256, 2)
__global__ void k_edge(const float* __restrict__ dR, const float* __restrict__ sh1,
                       const int* __restrict__ senders, const int* __restrict__ receivers,
                       const float* __restrict__ s1, const float* __restrict__ v1,
                       const float* __restrict__ R0, const float* __restrict__ R1,
                       const float* __restrict__ R2,
                       float* __restrict__ a_s, float* __restrict__ a_v){
  __shared__ __align__(16) float lR1[64*64];
  __shared__ __align__(16) float lR2[64*192];
  int tid = threadIdx.x;
  for (int i=tid;i<4096;i+=256)  lR1[i]=R1[i];
  for (int i=tid;i<12288;i+=256) lR2[i]=R2[i];
  __syncthreads();
  int e = blockIdx.x*256 + tid;
  float rb[8];
  bessel8(dR, e, rb);
  float h1[64];
  #pragma unroll
  for (int j=0;j<64;j+=4){
    float a0=0,a1=0,a2=0,a3=0;
    #pragma unroll
    for (int k=0;k<8;k++){
      float r = rb[k];
      const float* wp = R0 + k*64 + j;
      a0 = fmaf(r, wp[0], a0); a1 = fmaf(r, wp[1], a1);
      a2 = fmaf(r, wp[2], a2); a3 = fmaf(r, wp[3], a3);
    }
    h1[j+0]=silu_f(a0*0.3535533905932738f);
    h1[j+1]=silu_f(a1*0.3535533905932738f);
    h1[j+2]=silu_f(a2*0.3535533905932738f);
    h1[j+3]=silu_f(a3*0.3535533905932738f);
  }
  float h2[64];
  #pragma unroll
  for (int j=0;j<64;j+=4){
    float a0=0,a1=0,a2=0,a3=0;
    #pragma unroll
    for (int k=0;k<64;k++){
      float h = h1[k];
      float4 w4 = *(const float4*)(lR1 + k*64 + j);
      a0 = fmaf(h,w4.x,a0); a1 = fmaf(h,w4.y,a1);
      a2 = fmaf(h,w4.z,a2); a3 = fmaf(h,w4.w,a3);
    }
    h2[j+0]=silu_f(a0*0.125f);
    h2[j+1]=silu_f(a1*0.125f);
    h2[j+2]=silu_f(a2*0.125f);
    h2[j+3]=silu_f(a3*0.125f);
  }
  int src = senders[e], dst = receivers[e];
  float sx=sh1[3*e+0], sy=sh1[3*e+1], sz=sh1[3*e+2];
  const float* srow = s1 + (size_t)src*64;
  const float* vrow = v1 + (size_t)src*96;
  float* asr = a_s + (size_t)dst*96;
  float* avr = a_v + (size_t)dst*288;
  #pragma unroll 1
  for (int o=0;o<64;o+=4){
    float w10=0,w11=0,w12=0,w13=0, w20=0,w21=0,w22=0,w23=0;
    #pragma unroll
    for (int k=0;k<64;k++){
      float h = h2[k];
      float4 wa = *(const float4*)(lR2 + k*192 + o);
      float4 wb = *(const float4*)(lR2 + k*192 + 64 + o);
      w10=fmaf(h,wa.x,w10); w11=fmaf(h,wa.y,w11); w12=fmaf(h,wa.z,w12); w13=fmaf(h,wa.w,w13);
      w20=fmaf(h,wb.x,w20); w21=fmaf(h,wb.y,w21); w22=fmaf(h,wb.z,w22); w23=fmaf(h,wb.w,w23);
    }
    float4 se4 = *(const float4*)(srow + o);
    float sev[4] = {se4.x, se4.y, se4.z, se4.w};
    float w1a[4] = {w10,w11,w12,w13};
    float w2a[4] = {w20,w21,w22,w23};
    #pragma unroll
    for (int u=0;u<4;u++){
      atomicAdd(asr+o+u, 0.03125f*w1a[u]*sev[u]);
      float m = 0.03125f*w2a[u]*sev[u];
      atomicAdd(avr+(o+u)*3+0, m*sx);
      atomicAdd(avr+(o+u)*3+1, m*sy);
      atomicAdd(avr+(o+u)*3+2, m*sz);
    }
  }
  #pragma unroll 1
  for (int i0=0;i0<32;i0+=4){
    float w30=0,w31=0,w32=0,w33=0, w40=0,w41=0,w42=0,w43=0;
    #pragma unroll
    for (int k=0;k<64;k++){
      float h = h2[k];
      float4 wa = *(const float4*)(lR2 + k*192 + 128 + i0);
      float4 wb = *(const float4*)(lR2 + k*192 + 160 + i0);
      w30=fmaf(h,wa.x,w30); w31=fmaf(h,wa.y,w31); w32=fmaf(h,wa.z,w32); w33=fmaf(h,wa.w,w33);
      w40=fmaf(h,wb.x,w40); w41=fmaf(h,wb.y,w41); w42=fmaf(h,wb.z,w42); w43=fmaf(h,wb.w,w43);
    }
    float w3a[4] = {w30,w31,w32,w33};
    float w4a[4] = {w40,w41,w42,w43};
    #pragma unroll
    for (int u=0;u<4;u++){
      int i = i0+u;
      float vx=vrow[3*i+0], vy=vrow[3*i+1], vz=vrow[3*i+2];
      float dv = vx*sx + vy*sy + vz*sz;
      atomicAdd(asr+64+i, 0.018042195912175807f*w4a[u]*dv);
      float m3 = 0.03125f*w3a[u];
      atomicAdd(avr+(64+i)*3+0, m3*vx);
      atomicAdd(avr+(64+i)*3+1, m3*vy);
      atomicAdd(avr+(64+i)*3+2, m3*vz);
    }
  }
}

// ---------------- per-layer output transform: o_s, o_v, gating ----------------
__global__ void k_out(const float* __restrict__ a_s, const float* __restrict__ a_v,
                      const float* __restrict__ scs, const float* __restrict__ scv,
                      const float* __restrict__ W2s, const float* __restrict__ W2v,
                      float* __restrict__ s_out, float* __restrict__ v_out){
  __shared__ float las[2][96];
  __shared__ float lav[2][288];
  __shared__ float los[2][96];
  int tid = threadIdx.x;
  int j = tid>>7, t = tid&127;
  int n = blockIdx.x*2 + j;
  for (int i=t;i<96;i+=128)  las[j][i]=a_s[(size_t)n*96+i];
  for (int i=t;i<288;i+=128) lav[j][i]=a_v[(size_t)n*288+i];
  __syncthreads();
  if (t<96){
    float acc=0.0f;
    #pragma unroll 8
    for (int i=0;i<96;i++) acc += las[j][i]*W2s[i*96+t];
    los[j][t] = acc*0.10206207261596575f + scs[(size_t)n*96+t];
  }
  __syncthreads();
  if (t<64) s_out[(size_t)n*64+t] = silu_f(los[j][t]);
  if (t<96){
    int op=t/3, c=t-3*op;
    float acc=0.0f;
    #pragma unroll 8
    for (int i=0;i<96;i++) acc += lav[j][i*3+c]*W2v[i*32+op];
    float ov = acc*0.10206207261596575f + scv[(size_t)n*96+t];
    float g = silu_f(los[j][64+op]);
    v_out[(size_t)n*96+t] = ov*g;
  }
}

// ---------------- final heads: energy + mags ----------------
__global__ void k_final(const float* __restrict__ s, const float* __restrict__ nodes,
                        const int* __restrict__ n_node,
                        const float* __restrict__ Wen1, const float* __restrict__ Wen2,
                        const float* __restrict__ Wm1, const float* __restrict__ Wm2,
                        const float* __restrict__ scale_occ, const float* __restrict__ shift_occ,
                        const float* __restrict__ escale, const float* __restrict__ eshift,
                        float* __restrict__ out){
  __shared__ float eacc[NG];
  __shared__ int goff[NG+1];
  int tid = threadIdx.x;
  if (tid < NG) eacc[tid] = 0.0f;
  if (tid == 0){
    int c = 0; goff[0] = 0;
    for (int g=0; g<NG; g++){ c += n_node[g]; goff[g+1] = c; }
  }
  __syncthreads();
  int n = blockIdx.x*256 + tid;
  if (n < NN){
    float sv[64];
    #pragma unroll
    for (int i=0;i<64;i++) sv[i]=s[(size_t)n*64+i];
    float en=0.0f, m0=0.0f, m1=0.0f;
    #pragma unroll 1
    for (int jj=0;jj<32;jj++){
      float he=0.0f, hm=0.0f;
      #pragma unroll
      for (int i=0;i<64;i++){
        he = fmaf(sv[i], Wen1[i*32+jj], he);
        hm = fmaf(sv[i], Wm1[i*32+jj], hm);
      }
      he *= 0.125f; hm *= 0.125f;
      en = fmaf(he, Wen2[jj], en);
      m0 = fmaf(hm, Wm2[jj*2+0], m0);
      m1 = fmaf(hm, Wm2[jj*2+1], m1);
    }
    const float INVS32 = 0.17677669529663687f;
    en *= INVS32; m0 *= INVS32; m1 *= INVS32;
    en = escale[0]*en + eshift[0];
    int g = 0;
    for (int gg=0; gg<NG; gg++) if (n >= goff[gg+1]) g = gg+1;
    atomicAdd(&eacc[g], en);
    float nx=nodes[n*4+0], ny=nodes[n*4+1], nz=nodes[n*4+2];
    float sc0 = nx*scale_occ[0] + ny*scale_occ[2] + nz*scale_occ[4];
    float sc1 = nx*scale_occ[1] + ny*scale_occ[3] + nz*scale_occ[5];
    float sf0 = nx*shift_occ[0] + ny*shift_occ[2] + nz*shift_occ[4];
    float sf1 = nx*shift_occ[1] + ny*shift_occ[3] + nz*shift_occ[5];
    out[16 + n*2 + 0] = sc0*m0 + sf0;
    out[16 + n*2 + 1] = sc1*m1 + sf1;
  }
  __syncthreads();
  if (tid < NG) atomicAdd(&out[tid], eacc[tid]);
}

extern "C" void kernel_launch(void* const* d_in, const int* in_sizes, int n_in,
                              void* d_out, int out_size, void* d_ws, size_t ws_size,
                              hipStream_t stream){
  const float* nodes   = (const float*)d_in[0];
  const float* dR      = (const float*)d_in[1];
  const int*  senders  = (const int*)d_in[2];
  const int*  receivers= (const int*)d_in[3];
  const int*  n_node   = (const int*)d_in[4];
  const float* W_embed = (const float*)d_in[5];
  const float* W_sc_s  = (const float*)d_in[6];
  const float* W_sc_v  = (const float*)d_in[7];
  const float* W_l1_s  = (const float*)d_in[8];
  const float* W_l1_v  = (const float*)d_in[9];
  const float* Wr0     = (const float*)d_in[10];
  const float* Wr1     = (const float*)d_in[11];
  const float* Wr2     = (const float*)d_in[12];
  const float* W_l2_s  = (const float*)d_in[13];
  const float* W_l2_v  = (const float*)d_in[14];
  const float* W_en1   = (const float*)d_in[15];
  const float* W_en2   = (const float*)d_in[16];
  const float* W_mag1  = (const float*)d_in[17];
  const float* W_mag2  = (const float*)d_in[18];
  const float* scale_occ = (const float*)d_in[19];
  const float* shift_occ = (const float*)d_in[20];
  const float* escale  = (const float*)d_in[21];
  const float* eshift  = (const float*)d_in[22];
  float* out = (float*)d_out;
  float* ws  = (float*)d_ws;

  // ---- workspace map (floats) — base footprint 77.04 MB ----
  float* sh1  = ws + 0;         // 960,000
  float* sA   = ws + 960000;    // 1,280,000
  float* vA   = ws + 2240000;   // 1,920,000
  float* s1   = ws + 4160000;   // 1,280,000
  float* v1   = ws + 5440000;   // 1,920,000
  float* scs  = ws + 7360000;   // 1,920,000
  float* scv  = ws + 9280000;   // 1,920,000
  float* a_s  = ws + 11200000;  // 1,920,000
  float* a_v  = ws + 13120000;  // 5,760,000  -> ends 18,880,000
  int*   cnt  = (int*)(ws + 18880000);  // 20,000
  int*   row  = (int*)(ws + 18900000);  // 20,001
  int*   cur  = (int*)(ws + 18920004);  // 20,000
  int*   perm = (int*)(ws + 18940004);  // 320,000 -> ends 19,260,004
  float* wbuf = ws + 19260008;          // capacity-adaptive, 16B-aligned

  size_t wsf = ws_size / 4;
  size_t cap_edges = (wsf > 19260008) ? (wsf - 19260008) / 192 : 0;
  const bool fast = cap_edges >= 4096;
  int cap = (int)((cap_edges > (size_t)NE) ? (size_t)NE + 8192 : cap_edges);
  // nodes per chunk: expected edges = 16*npc = 0.8*cap  (>35 sigma margin)
  int npc = (int)(cap / 20); if (npc < 1) npc = 1; if (npc > NN) npc = NN;
  int nchunk = (NN + npc - 1) / npc;

  hipMemsetAsync(vA, 0, (size_t)NN*96*sizeof(float), stream);   // v starts at zero
  hipMemsetAsync(out, 0, 16*sizeof(float), stream);             // energy accumulators

  k_geom<<<1250, 256, 0, stream>>>(dR, sh1);
  k_embed<<<5000, 256, 0, stream>>>(nodes, W_embed, sA);

  if (fast){
    hipMemsetAsync(cnt, 0, NN*sizeof(int), stream);
    k_hist<<<1250, 256, 0, stream>>>(receivers, cnt);
    k_scan<<<1, 1024, 0, stream>>>(cnt, row, cur);
    k_scatter<<<1250, 256, 0, stream>>>(receivers, cur, perm);
  }

  for (int l=0; l<2; l++){
    k_node<<<5000, 256, 0, stream>>>(sA, vA, nodes,
                                     W_l1_s + l*4096, W_l1_v + l*1024,
                                     W_sc_s + l*24576, W_sc_v + l*4096,
                                     s1, v1, scs, scv);
    if (fast){
      for (int ck=0; ck<nchunk; ck++){
        int n0 = ck*npc;
        int n1 = n0 + npc; if (n1 > NN) n1 = NN;
        int cover = (n1-n0)*17 + 4096; if (cover > cap) cover = cap;
        k_edgew<<<(cover+255)/256, 256, 0, stream>>>(dR, perm, row, n0, n1, cap,
                                       Wr0 + l*512, Wr1 + l*4096, Wr2 + l*12288, wbuf);
        k_gather<<<n1-n0, 384, 0, stream>>>(wbuf, perm, row, senders, sh1, s1, v1,
                                            n0, cap, a_s, a_v);
      }
    } else {
      hipMemsetAsync(a_s, 0, (size_t)NN*384*sizeof(float), stream);  // a_s+a_v contiguous
      k_edge<<<1250, 256, 0, stream>>>(dR, sh1, senders, receivers, s1, v1,
                                       Wr0 + l*512, Wr1 + l*4096, Wr2 + l*12288,
                                       a_s, a_v);
    }
    // writes back into sA/vA (safe: k_out reads only a_s/a_v/scs/scv)
    k_out<<<10000, 256, 0, stream>>>(a_s, a_v, scs, scv,
                                     W_l2_s + l*9216, W_l2_v + l*3072,
                                     sA, vA);
  }
  k_final<<<79, 256, 0, stream>>>(sA, nodes, n_node, W_en1, W_en2, W_mag1, W_mag2,
                                  scale_occ, shift_occ, escale, eshift, out);
}